// Round 6
// baseline (205.113 us; speedup 1.0000x reference)
//
#include <hip/hip_runtime.h>
#include <math.h>
#include <stdint.h>

#define S 2048
#define DMOD 1024
#define H 16

typedef unsigned short ushort_t;
typedef short bf16x8 __attribute__((ext_vector_type(8)));
typedef float f32x4 __attribute__((ext_vector_type(4)));

// chunk swizzle: rows 1..7 apart and 8 apart land on different chunk columns
#define SW(r) ((((r) & 7)) ^ ((((r) >> 3) & 3) << 1))

__device__ __forceinline__ ushort_t f2b(float f) {
    union { float f; unsigned u; } x; x.f = f;
    return (ushort_t)((x.u + 0x7FFFu + ((x.u >> 16) & 1u)) >> 16);
}
__device__ __forceinline__ float b2f(ushort_t b) {
    union { unsigned u; float f; } x; x.u = ((unsigned)b) << 16;
    return x.f;
}
__device__ __forceinline__ void gld16(const ushort_t* g, ushort_t* l) {
    __builtin_amdgcn_global_load_lds(
        (const __attribute__((address_space(1))) unsigned int*)g,
        (__attribute__((address_space(3))) unsigned int*)l, 16, 0, 0);
}

// ---------------------------------------------------------------------------
// One init kernel: zero attn_raw (2M fl), zero d_out (2M fl), init sumexp=t,
// zero corr. Grid 4129 x 256.
// ---------------------------------------------------------------------------
__global__ __launch_bounds__(256) void init_all(
    float* __restrict__ attn_raw, float* __restrict__ out,
    float* __restrict__ sumexp, float* __restrict__ corr)
{
    const int b = blockIdx.x;
    const float4 z4 = {0.f, 0.f, 0.f, 0.f};
    if (b < 2048) {
        *(float4*)(attn_raw + ((size_t)b * 256 + threadIdx.x) * 4) = z4;
    } else if (b < 4096) {
        *(float4*)(out + ((size_t)(b - 2048) * 256 + threadIdx.x) * 4) = z4;
    } else if (b < 4128) {
        int e = ((b - 4096) * 256 + threadIdx.x) * 4;
        float4 v = {(float)(e & 2047), (float)((e + 1) & 2047),
                    (float)((e + 2) & 2047), (float)((e + 3) & 2047)};
        *(float4*)(sumexp + e) = v;
    } else {
        *(float4*)(corr + threadIdx.x * 4) = z4;
    }
}

// ---------------------------------------------------------------------------
__global__ __launch_bounds__(256) void convert_all(
    const float* q, const float* k, const float* v,
    const float* wq, const float* wk, const float* wv, const float* wo,
    ushort_t* qo, ushort_t* ko, ushort_t* vo,
    ushort_t* wqo, ushort_t* wko, ushort_t* wvo, ushort_t* woo)
{
    const int seg = blockIdx.y;
    const float* src; ushort_t* dst; size_t off = 0;
    const size_t M1 = (size_t)1 << 20;
    if (seg < 2)       { src = q;  dst = qo;  off = (size_t)seg * M1; }
    else if (seg < 4)  { src = k;  dst = ko;  off = (size_t)(seg - 2) * M1; }
    else if (seg < 6)  { src = v;  dst = vo;  off = (size_t)(seg - 4) * M1; }
    else if (seg == 6) { src = wq; dst = wqo; }
    else if (seg == 7) { src = wk; dst = wko; }
    else if (seg == 8) { src = wv; dst = wvo; }
    else               { src = wo; dst = woo; }
    size_t i = off + ((size_t)blockIdx.x * 256 + threadIdx.x) * 4;
    float4 f = *(const float4*)(src + i);
    union { uint2 u2; ushort_t us[4]; } o;
    o.us[0] = f2b(f.x); o.us[1] = f2b(f.y); o.us[2] = f2b(f.z); o.us[3] = f2b(f.w);
    *(uint2*)(dst + i) = o.u2;
}

// ---------------------------------------------------------------------------
// Fused QKV projection GEMM: block tile 128x64 over N=3072 (Q|K|V).
// ---------------------------------------------------------------------------
__global__ __launch_bounds__(256) void gemm_qkv(
    const ushort_t* __restrict__ A0, const ushort_t* __restrict__ A1,
    const ushort_t* __restrict__ A2, const ushort_t* __restrict__ Wqkv,
    const float* __restrict__ b0, const float* __restrict__ b1,
    const float* __restrict__ b2,
    ushort_t* __restrict__ qbb, ushort_t* __restrict__ kbb,
    ushort_t* __restrict__ vt)
{
    __shared__ ushort_t As[128 * 64];
    __shared__ ushort_t Bs[64 * 64];
    const int tid = threadIdx.x;
    const int lane = tid & 63, wid = tid >> 6;
    const int quad = lane >> 4, l15 = lane & 15;
    const int wr = wid >> 1, wc = wid & 1;
    const int m0 = blockIdx.y * 128;
    const int n0 = blockIdx.x * 64;
    const int seg = n0 >> 10;
    const int nloc = n0 & 1023;
    const ushort_t* A = seg == 0 ? A0 : (seg == 1 ? A1 : A2);
    const float* bias = seg == 0 ? b0 : (seg == 1 ? b1 : b2);

    const f32x4 fz = {0.f, 0.f, 0.f, 0.f};
    f32x4 acc[4][2];
#pragma unroll
    for (int i = 0; i < 4; ++i) { acc[i][0] = fz; acc[i][1] = fz; }

    for (int k0 = 0; k0 < DMOD; k0 += 64) {
        __syncthreads();
#pragma unroll
        for (int i = 0; i < 4; ++i) {
            int c = i * 256 + tid, row = c >> 3, kcl = c & 7;
            gld16(A + (size_t)(m0 + row) * DMOD + k0 + (kcl ^ SW(row)) * 8, &As[c * 8]);
        }
#pragma unroll
        for (int i = 0; i < 2; ++i) {
            int c = i * 256 + tid, row = c >> 3, kcl = c & 7;
            gld16(Wqkv + (size_t)(n0 + row) * DMOD + k0 + (kcl ^ SW(row)) * 8, &Bs[c * 8]);
        }
        __syncthreads();
#pragma unroll
        for (int kc = 0; kc < 2; ++kc) {
            bf16x8 af[4], bfr[2];
#pragma unroll
            for (int mi = 0; mi < 4; ++mi) {
                int row = wr * 64 + mi * 16 + l15;
                af[mi] = *(const bf16x8*)&As[row * 64 + ((kc * 4 + quad) ^ SW(row)) * 8];
            }
#pragma unroll
            for (int ni = 0; ni < 2; ++ni) {
                int row = wc * 32 + ni * 16 + l15;
                bfr[ni] = *(const bf16x8*)&Bs[row * 64 + ((kc * 4 + quad) ^ SW(row)) * 8];
            }
#pragma unroll
            for (int mi = 0; mi < 4; ++mi)
#pragma unroll
                for (int ni = 0; ni < 2; ++ni)
                    acc[mi][ni] = __builtin_amdgcn_mfma_f32_16x16x32_bf16(
                        af[mi], bfr[ni], acc[mi][ni], 0, 0, 0);
        }
    }

    if (seg < 2) {
        ushort_t* C = seg == 0 ? qbb : kbb;
#pragma unroll
        for (int mi = 0; mi < 4; ++mi)
#pragma unroll
            for (int ni = 0; ni < 2; ++ni) {
                int gn = nloc + wc * 32 + ni * 16 + l15;
                float bv = bias[gn];
#pragma unroll
                for (int r = 0; r < 4; ++r) {
                    int gm = m0 + wr * 64 + mi * 16 + quad * 4 + r;
                    C[(size_t)gm * DMOD + gn] = f2b(acc[mi][ni][r] + bv);
                }
            }
    } else {
#pragma unroll
        for (int mi = 0; mi < 4; ++mi)
#pragma unroll
            for (int ni = 0; ni < 2; ++ni) {
                int gn = nloc + wc * 32 + ni * 16 + l15;   // v_global
                float bv = bias[gn];
                int gmb = m0 + wr * 64 + mi * 16 + quad * 4;
                union { uint2 u2; ushort_t us[4]; } o;
#pragma unroll
                for (int r = 0; r < 4; ++r) o.us[r] = f2b(acc[mi][ni][r] + bv);
                *(uint2*)&vt[(size_t)gn * S + gmb] = o.u2;
            }
    }
}

// ---------------------------------------------------------------------------
// Attention core v4: same tiling as v3 (s-tile 128, 8 waves, t-half split,
// double-buffered K/V) but with AITER-style fine-grained waits:
//  - raw `s_waitcnt lgkmcnt(0); s_barrier` per step (NO vmcnt drain)
//  - explicit `s_waitcnt vmcnt(2)` before reading the current K/V buffer,
//    leaving the 2 just-issued next-step prefetches in flight.
// In-loop VMEM is exactly 2 global_load_lds per thread per step, so vmcnt(2)
// is the precise "wait for current buffer, not the prefetch" condition.
// ---------------------------------------------------------------------------
__global__ __launch_bounds__(512, 4) void attn_mfma(
    const ushort_t* __restrict__ qb, const ushort_t* __restrict__ kb,
    const ushort_t* __restrict__ vt, float* __restrict__ attn_raw,
    float* __restrict__ sumexp)
{
    __shared__ ushort_t Qs[128 * 64];
    __shared__ ushort_t Ks[2][4096];
    __shared__ ushort_t Vs[2][4096];
    __shared__ ushort_t Ps[128 * 64];
    __shared__ float    sacc[1024];

    const int h = blockIdx.y;
    const int bx = blockIdx.x;
    const int si = 15 - (bx >> 1);     // long blocks dispatch first
    const int z = bx & 1;
    const int half = si + 1;           // steps per z-block (balanced)
    const int tbeg = z ? half : 0;
    const int tend = z ? 2 * si + 2 : half;
    const int s0 = si * 128;

    const int tid = threadIdx.x;
    const int lane = tid & 63, w = tid >> 6;
    const int quad = lane >> 4, l15 = lane & 15;
    const int sband = s0 + w * 16;     // wave's lowest s row

    const ushort_t* qh = qb + h * 64;
    const ushort_t* kh = kb + h * 64;
    const ushort_t* vh = vt + (size_t)(h * 64) * S;

    // stage Q (128x64) + first K/V into buf 0
#pragma unroll
    for (int i = 0; i < 2; ++i) {
        int c = i * 512 + tid, row = c >> 3, kcl = c & 7;
        gld16(qh + (size_t)(s0 + row) * DMOD + (kcl ^ SW(row)) * 8, &Qs[c * 8]);
    }
    {
        int t0 = tbeg * 64;
        int row = tid >> 3, kcl = tid & 7;
        gld16(kh + (size_t)(t0 + row) * DMOD + (kcl ^ SW(row)) * 8, &Ks[0][tid * 8]);
        gld16(vh + (size_t)row * S + t0 + (kcl ^ SW(row)) * 8, &Vs[0][tid * 8]);
    }
    for (int i = tid; i < 1024; i += 512) sacc[i] = 0.f;
    __syncthreads();   // full drain: Q + initial K/V landed, sacc zeroed

    // hoist step-invariant Q fragments
    bf16x8 aq[2];
    {
        int rq = w * 16 + l15;
#pragma unroll
        for (int kc = 0; kc < 2; ++kc)
            aq[kc] = *(const bf16x8*)&Qs[rq * 64 + ((kc * 4 + quad) ^ SW(rq)) * 8];
    }

    const f32x4 fz = {0.f, 0.f, 0.f, 0.f};
    f32x4 oacc[4];
#pragma unroll
    for (int ni = 0; ni < 4; ++ni) oacc[ni] = fz;

    for (int it = tbeg; it < tend; ++it) {
        const int p = (it - tbeg) & 1;
        const int t0 = it * 64;
        // prefetch next K/V into the other buffer; stays in flight across
        // this step's compute AND the raw barrier below.
        if (it + 1 < tend) {
            int t1 = t0 + 64;
            int row = tid >> 3, kcl = tid & 7;
            gld16(kh + (size_t)(t1 + row) * DMOD + (kcl ^ SW(row)) * 8, &Ks[1 - p][tid * 8]);
            gld16(vh + (size_t)row * S + t1 + (kcl ^ SW(row)) * 8, &Vs[1 - p][tid * 8]);
        }

        if (t0 < sband + 16) {   // not fully masked for this wave band
            // wait for current buffer only: the 2 newest outstanding loads
            // (next-step prefetch) may remain in flight.
            asm volatile("s_waitcnt vmcnt(2)" ::: "memory");

            // X = Q K^T
            f32x4 xf[4];
#pragma unroll
            for (int ti = 0; ti < 4; ++ti) xf[ti] = fz;
#pragma unroll
            for (int kc = 0; kc < 2; ++kc) {
#pragma unroll
                for (int ti = 0; ti < 4; ++ti) {
                    int rk = ti * 16 + l15;
                    bf16x8 bk = *(const bf16x8*)&Ks[p][rk * 64 + ((kc * 4 + quad) ^ SW(rk)) * 8];
                    xf[ti] = __builtin_amdgcn_mfma_f32_16x16x32_bf16(aq[kc], bk, xf[ti], 0, 0, 0);
                }
            }

            // scale, mask, exp column sums -> LDS, P -> wave-private LDS
            const bool clean = (t0 + 63 <= sband);   // no masking possible
            const int s_q = sband + quad * 4;
#pragma unroll
            for (int ti = 0; ti < 4; ++ti) {
                int t_g = t0 + ti * 16 + l15;
                float es = 0.f;
#pragma unroll
                for (int r = 0; r < 4; ++r) {
                    float xv = xf[ti][r] * 0.125f;
                    bool live = clean || (s_q + r >= t_g);
                    xv = live ? xv : 0.f;
                    es += live ? __expf(xv) : 0.f;
                    xf[ti][r] = xv;
                }
                es += __shfl_xor(es, 16, 64);
                es += __shfl_xor(es, 32, 64);
                if (quad == 0) atomicAdd(&sacc[t0 - tbeg * 64 + ti * 16 + l15], es);
#pragma unroll
                for (int r = 0; r < 4; ++r) {
                    int sl = w * 16 + quad * 4 + r;
                    int tc = ti * 16 + l15;
                    Ps[sl * 64 + ((tc >> 3) ^ SW(sl)) * 8 + (tc & 7)] = f2b(xf[ti][r]);
                }
            }

            // O += P V   (reads only this wave's Ps rows)
#pragma unroll
            for (int kc = 0; kc < 2; ++kc) {
                int rp = w * 16 + l15;
                bf16x8 ap = *(const bf16x8*)&Ps[rp * 64 + ((kc * 4 + quad) ^ SW(rp)) * 8];
#pragma unroll
                for (int ni = 0; ni < 4; ++ni) {
                    int rv = ni * 16 + l15;
                    bf16x8 bv = *(const bf16x8*)&Vs[p][rv * 64 + ((kc * 4 + quad) ^ SW(rv)) * 8];
                    oacc[ni] = __builtin_amdgcn_mfma_f32_16x16x32_bf16(ap, bv, oacc[ni], 0, 0, 0);
                }
            }
        }
        // raw barrier: drain own DS ops (LDS WAR safety) but leave the
        // prefetch's vmcnt outstanding — the whole point of this round.
        asm volatile("s_waitcnt lgkmcnt(0)\n\ts_barrier" ::: "memory");
    }

    // exp-sum burst: one global atomic per covered t
    {
        int nv = (tend - tbeg) * 64;
        for (int i = tid; i < nv; i += 512)
            atomicAdd(&sumexp[h * S + tbeg * 64 + i], sacc[i]);
    }
    // O accumulate (two z-blocks per (h,si) sum into zeroed attn_raw)
#pragma unroll
    for (int ni = 0; ni < 4; ++ni)
#pragma unroll
        for (int r = 0; r < 4; ++r) {
            int s_g = s0 + w * 16 + quad * 4 + r;
            atomicAdd(&attn_raw[(size_t)s_g * DMOD + h * 64 + ni * 16 + l15],
                      oacc[ni][r]);
        }
}

// ---------------------------------------------------------------------------
// corr[r=h*64+j] = sum_t log(sumexp[h,t]) * vt[r][t]; one wave per row.
// ---------------------------------------------------------------------------
__global__ __launch_bounds__(256) void corr_kernel(
    const float* __restrict__ sumexp, const ushort_t* __restrict__ vt,
    float* __restrict__ corr)
{
    const int w = threadIdx.x >> 6, lane = threadIdx.x & 63;
    const int r = blockIdx.x * 4 + w;       // 0..1023
    const int h = r >> 6;
    float acc = 0.f;
#pragma unroll
    for (int i = 0; i < 4; ++i) {
        int t = i * 512 + lane * 8;
        bf16x8 vv = *(const bf16x8*)&vt[(size_t)r * S + t];
        float4 s0 = *(const float4*)&sumexp[h * S + t];
        float4 s1 = *(const float4*)&sumexp[h * S + t + 4];
        acc += logf(s0.x) * b2f((ushort_t)vv[0]) + logf(s0.y) * b2f((ushort_t)vv[1])
             + logf(s0.z) * b2f((ushort_t)vv[2]) + logf(s0.w) * b2f((ushort_t)vv[3])
             + logf(s1.x) * b2f((ushort_t)vv[4]) + logf(s1.y) * b2f((ushort_t)vv[5])
             + logf(s1.z) * b2f((ushort_t)vv[6]) + logf(s1.w) * b2f((ushort_t)vv[7]);
    }
#pragma unroll
    for (int d = 1; d < 64; d <<= 1) acc += __shfl_xor(acc, d, 64);
    if (lane == 0) corr[r] = acc;
}

// ---------------------------------------------------------------------------
__global__ __launch_bounds__(256) void convert_Z(
    const float* __restrict__ attn_raw, const float* __restrict__ corr,
    ushort_t* __restrict__ Zb)
{
    size_t i = ((size_t)blockIdx.x * 256 + threadIdx.x) * 4;
    float4 f = *(const float4*)(attn_raw + i);
    int c = (int)(i & (DMOD - 1));
    union { uint2 u2; ushort_t us[4]; } o;
    o.us[0] = f2b(f.x - corr[c]);
    o.us[1] = f2b(f.y - corr[c + 1]);
    o.us[2] = f2b(f.z - corr[c + 2]);
    o.us[3] = f2b(f.w - corr[c + 3]);
    *(uint2*)(Zb + i) = o.u2;
}

// ---------------------------------------------------------------------------
// Output GEMM, split-K=2, atomic fp32 epilogue (d_out zeroed by init_all).
// ---------------------------------------------------------------------------
__global__ __launch_bounds__(256) void gemm_out(
    const ushort_t* __restrict__ A, const ushort_t* __restrict__ W,
    const float* __restrict__ bias, float* __restrict__ C)
{
    __shared__ ushort_t As[128 * 64];
    __shared__ ushort_t Bs[64 * 64];
    const int tid = threadIdx.x;
    const int lane = tid & 63, wid = tid >> 6;
    const int quad = lane >> 4, l15 = lane & 15;
    const int wr = wid >> 1, wc = wid & 1;
    const int m0 = blockIdx.y * 128, n0 = blockIdx.x * 64;
    const int kbeg = blockIdx.z * 512, kend = kbeg + 512;

    const f32x4 fz = {0.f, 0.f, 0.f, 0.f};
    f32x4 acc[4][2];
#pragma unroll
    for (int i = 0; i < 4; ++i) { acc[i][0] = fz; acc[i][1] = fz; }

    for (int k0 = kbeg; k0 < kend; k0 += 64) {
        __syncthreads();
#pragma unroll
        for (int i = 0; i < 4; ++i) {
            int c = i * 256 + tid, row = c >> 3, kcl = c & 7;
            gld16(A + (size_t)(m0 + row) * DMOD + k0 + (kcl ^ SW(row)) * 8, &As[c * 8]);
        }
#pragma unroll
        for (int i = 0; i < 2; ++i) {
            int c = i * 256 + tid, row = c >> 3, kcl = c & 7;
            gld16(W + (size_t)(n0 + row) * DMOD + k0 + (kcl ^ SW(row)) * 8, &Bs[c * 8]);
        }
        __syncthreads();
#pragma unroll
        for (int kc = 0; kc < 2; ++kc) {
            bf16x8 af[4], bfr[2];
#pragma unroll
            for (int mi = 0; mi < 4; ++mi) {
                int row = wr * 64 + mi * 16 + l15;
                af[mi] = *(const bf16x8*)&As[row * 64 + ((kc * 4 + quad) ^ SW(row)) * 8];
            }
#pragma unroll
            for (int ni = 0; ni < 2; ++ni) {
                int row = wc * 32 + ni * 16 + l15;
                bfr[ni] = *(const bf16x8*)&Bs[row * 64 + ((kc * 4 + quad) ^ SW(row)) * 8];
            }
#pragma unroll
            for (int mi = 0; mi < 4; ++mi)
#pragma unroll
                for (int ni = 0; ni < 2; ++ni)
                    acc[mi][ni] = __builtin_amdgcn_mfma_f32_16x16x32_bf16(
                        af[mi], bfr[ni], acc[mi][ni], 0, 0, 0);
        }
    }
#pragma unroll
    for (int mi = 0; mi < 4; ++mi)
#pragma unroll
        for (int ni = 0; ni < 2; ++ni) {
            int gn = n0 + wc * 32 + ni * 16 + l15;
            float bv = (kbeg == 0) ? bias[gn] : 0.f;
#pragma unroll
            for (int r = 0; r < 4; ++r) {
                int gm = m0 + wr * 64 + mi * 16 + quad * 4 + r;
                atomicAdd(&C[(size_t)gm * DMOD + gn], acc[mi][ni][r] + bv);
            }
        }
}

// ---------------------------------------------------------------------------
extern "C" void kernel_launch(void* const* d_in, const int* in_sizes, int n_in,
                              void* d_out, int out_size, void* d_ws, size_t ws_size,
                              hipStream_t stream) {
    const float* Qin = (const float*)d_in[0];
    const float* Kin = (const float*)d_in[1];
    const float* Vin = (const float*)d_in[2];
    const float* WQw = (const float*)d_in[3];
    const float* WQb = (const float*)d_in[4];
    const float* WKw = (const float*)d_in[5];
    const float* WKb = (const float*)d_in[6];
    const float* WVw = (const float*)d_in[7];
    const float* WVb = (const float*)d_in[8];
    const float* WOw = (const float*)d_in[9];
    const float* WOb = (const float*)d_in[10];

    float* ws = (float*)d_ws;
    const size_t M1 = (size_t)1 << 20;
    ushort_t* qbb  = (ushort_t*)(ws);                 // [2048][1024] bf16
    ushort_t* kbb  = (ushort_t*)(ws + M1);
    ushort_t* vt   = (ushort_t*)(ws + 2 * M1);        // [1024 v][2048 t] bf16
    ushort_t* wqkv = (ushort_t*)(ws + 3 * M1);        // [3072][1024] bf16
    ushort_t* wob  = (ushort_t*)(ws + 4 * M1 + M1 / 2);
    ushort_t* Qbin = (ushort_t*)(ws + 5 * M1);        // reused as Zb
    ushort_t* Kbin = (ushort_t*)(ws + 6 * M1);        // \ reused as
    ushort_t* Vbin = (ushort_t*)(ws + 7 * M1);        // / attn_raw (2M fl)
    float* attn_raw = ws + 6 * M1;
    ushort_t* Zb    = (ushort_t*)(ws + 5 * M1);
    float* sumexp   = ws + 8 * M1;                    // 32768
    float* corr     = ws + 8 * M1 + H * S;            // 1024

    init_all<<<4129, 256, 0, stream>>>(attn_raw, (float*)d_out, sumexp, corr);

    convert_all<<<dim3(1024, 10), 256, 0, stream>>>(
        Qin, Kin, Vin, WQw, WKw, WVw, WOw,
        Qbin, Kbin, Vbin,
        wqkv, wqkv + (size_t)1024 * 1024, wqkv + (size_t)2 * 1024 * 1024, wob);

    gemm_qkv<<<dim3(48, 16), 256, 0, stream>>>(
        Qbin, Kbin, Vbin, wqkv, WQb, WKb, WVb, qbb, kbb, vt);

    attn_mfma<<<dim3(32, H), 512, 0, stream>>>(qbb, kbb, vt, attn_raw, sumexp);

    corr_kernel<<<256, 256, 0, stream>>>(sumexp, vt, corr);
    convert_Z<<<2048, 256, 0, stream>>>(attn_raw, corr, Zb);

    gemm_out<<<dim3(16, 16, 2), 256, 0, stream>>>(Zb, wob, WOb, (float*)d_out);
}